// Round 18
// baseline (2005.253 us; speedup 1.0000x reference)
//
#include <hip/hip_runtime.h>
#include <hip/hip_bf16.h>

// Grouped Residual VQ: G=2, Q=8, K=1024, CD=256, DIM=1280 (DG=640), T=32768.
//
// Round 18 = r17 with the LDS buffer size FIXED (CbV[2][2048], was [2][1024]
// -> staging and lo-plane reads overran buffer 0 into buffer 1, corrupting
// the double buffer; absmax 1024 on indices).
// Structure: 32-code chunks (2 planes x 1024 units = 32 KB/buf, dbuf 64 KB),
// refinement scratch aliases CbV[0]; ~68 KB LDS -> 2 blocks/CU so cross-
// block async overlap fills barrier/vmcnt stalls.

#define G 2
#define Q 8
#define KCODES 1024
#define CD 256
#define DIMV 1280
#define DG 640
#define T 32768
#define TM 128

#define WS_H      ((size_t)0)
#define WS_RES    (WS_H + (size_t)G*T*CD)
#define WS_CNORM  (WS_RES + (size_t)G*T*CD)
#define WS_CN64   (WS_CNORM + (size_t)G*Q*KCODES)
#define WS_LPARTD (WS_CN64 + (size_t)2*G*Q*KCODES)

#define OUT_IDX   ((size_t)T*DIMV)
#define OUT_LOSS  (OUT_IDX + (size_t)G*T*Q)

#define EPS_REFINE 2e-3f
#define ERRB 1e-3

typedef __attribute__((ext_vector_type(8))) short s16x8;
typedef __attribute__((ext_vector_type(4))) float f32x4;

static __device__ __forceinline__ unsigned short f2bf(float v) {
    __hip_bfloat16 b = __float2bfloat16(v);
    return *(unsigned short*)&b;
}
static __device__ __forceinline__ float bf2f(unsigned short u) {
    __hip_bfloat16 b = *(__hip_bfloat16*)&u;
    return __bfloat162float(b);
}

static __device__ __forceinline__ void gl_lds16(const void* g, void* l) {
    __builtin_amdgcn_global_load_lds(
        (const __attribute__((address_space(1))) unsigned int*)g,
        (__attribute__((address_space(3))) unsigned int*)l, 16, 0, 0);
}

__device__ __forceinline__ float np_half_sumsq(const float4* __restrict__ p) {
    float4 a = p[0], b = p[1];
    float r0=a.x*a.x, r1=a.y*a.y, r2=a.z*a.z, r3=a.w*a.w;
    float r4=b.x*b.x, r5=b.y*b.y, r6=b.z*b.z, r7=b.w*b.w;
#pragma unroll
    for (int i = 1; i < 16; i++) {
        a = p[2*i]; b = p[2*i+1];
        r0 += a.x*a.x; r1 += a.y*a.y; r2 += a.z*a.z; r3 += a.w*a.w;
        r4 += b.x*b.x; r5 += b.y*b.y; r6 += b.z*b.z; r7 += b.w*b.w;
    }
    return ((r0+r1)+(r2+r3)) + ((r4+r5)+(r6+r7));
}

// ---------------- K1: codebook norms (f32 + exact f64) ----------------
__global__ void k_norms(const float* __restrict__ cb, float* __restrict__ ws) {
    int r = blockIdx.x * 256 + threadIdx.x;
    const float4* row = (const float4*)(cb + (size_t)r * CD);
    ws[WS_CNORM + r] = np_half_sumsq(row) + np_half_sumsq(row + 32);
    double s0=0, s1=0, s2=0, s3=0;
#pragma unroll 8
    for (int e = 0; e < 64; e++) {
        float4 v = row[e];
        s0 = fma((double)v.x,(double)v.x,s0); s1 = fma((double)v.y,(double)v.y,s1);
        s2 = fma((double)v.z,(double)v.z,s2); s3 = fma((double)v.w,(double)v.w,s3);
    }
    ((double*)(ws + WS_CN64))[r] = (s0+s1)+(s2+s3);
}

// ---------------- K1b: codebook bf16 hi/lo split + LDS-order transpose ----------------
// cbt unit order: [(gq*32+cc32)*2+pl][dc 8][ku 4][code32 32] (16B units).
__global__ void k_split(const float* __restrict__ cb, short* __restrict__ cbt) {
    int tau = blockIdx.x * 256 + threadIdx.x;     // 0 .. G*Q*KCODES*32-1
    int u = tau & 31;                             // dim unit within row
    int row = tau >> 5;                           // global code row 0..G*Q*K-1
    int gq = row >> 10;
    int code = row & 1023;
    int cc = code >> 5, c32 = code & 31;
    const float* src = cb + (size_t)row * CD + u * 8;
    float4 v0 = *(const float4*)src;
    float4 v1 = *(const float4*)(src + 4);
    float v[8] = {v0.x,v0.y,v0.z,v0.w,v1.x,v1.y,v1.z,v1.w};
    s16x8 hh, ll;
#pragma unroll
    for (int e = 0; e < 8; e++) {
        unsigned short hb = f2bf(v[e]);
        hh[e] = (short)hb;
        ll[e] = (short)f2bf(v[e] - bf2f(hb));
    }
    int n = (u >> 2) * 128 + (u & 3) * 32 + c32;  // dc*128 + ku*32 + code32
    size_t base = ((size_t)(gq * 32 + cc) * 2) * 1024;
    *(s16x8*)(cbt + (base + n) * 8)        = hh;  // plane 0 (hi)
    *(s16x8*)(cbt + (base + 1024 + n) * 8) = ll;  // plane 1 (lo)
}

// ---------------- K2: input projection h = x_g @ Win_g^T + bin ----------------
__global__ __launch_bounds__(256) void k_proj_in(const float* __restrict__ x,
                                                 const float* __restrict__ Win,
                                                 const float* __restrict__ bin,
                                                 float* __restrict__ ws) {
    __shared__ float As[32][65];
    __shared__ float Bs[32][65];
    const int g  = blockIdx.z;
    const int t0 = blockIdx.x * 64;
    const int c0 = blockIdx.y * 64;
    const int tid = threadIdx.x;
    const int tx = tid & 15, ty = tid >> 4;
    float acc[4][4] = {};
    const float* Ab = x + (size_t)t0 * DIMV + (size_t)g * DG;
    const float* Bb = Win + (size_t)g * CD * DG + (size_t)c0 * DG;

    for (int k0 = 0; k0 < DG; k0 += 32) {
        __syncthreads();
#pragma unroll
        for (int j = 0; j < 8; j++) {
            int lin = j * 256 + tid;
            int k = lin & 31, r = lin >> 5;
            As[k][r] = Ab[(size_t)r * DIMV + k0 + k];
            Bs[k][r] = Bb[(size_t)r * DG + k0 + k];
        }
        __syncthreads();
#pragma unroll
        for (int k = 0; k < 32; k++) {
            float a[4], b[4];
#pragma unroll
            for (int i = 0; i < 4; i++) a[i] = As[k][ty + 16 * i];
#pragma unroll
            for (int j = 0; j < 4; j++) b[j] = Bs[k][tx + 16 * j];
#pragma unroll
            for (int i = 0; i < 4; i++)
#pragma unroll
                for (int j = 0; j < 4; j++) acc[i][j] = fmaf(a[i], b[j], acc[i][j]);
        }
    }
#pragma unroll
    for (int i = 0; i < 4; i++) {
        int t = t0 + ty + 16 * i;
        float* hrow = ws + WS_H + ((size_t)g * T + t) * CD;
#pragma unroll
        for (int j = 0; j < 4; j++) {
            int c = c0 + tx + 16 * j;
            hrow[c] = acc[i][j] + bin[g * CD + c];
        }
    }
}

// ---------------- K3: fused ResidualVQ (reg-resident residual, 2 blocks/CU) ----------------
#define STE1(rv, cv) { float tt_ = __fsub_rn((cv), (rv)); float qq_ = __fadd_rn((rv), tt_); \
                       float rr_ = __fsub_rn((rv), qq_); lacc += (double)rr_ * rr_; (rv) = rr_; }

__global__ __launch_bounds__(512, 2) void k_rvq(const float* __restrict__ cb,
                                                float* __restrict__ ws,
                                                float* __restrict__ out,
                                                const short* __restrict__ cbt) {
    __shared__ s16x8 CbV[2][2048];               // 64 KB: [pl 2][dc 8][ku 4][code32 32] x2 buf
    __shared__ float cnS[KCODES];                // 4 KB
    __shared__ double lredD[8];

    const int g  = blockIdx.y;
    const int t0 = blockIdx.x * TM;
    const int tid = threadIdx.x;
    const int lane = tid & 63, l15 = lane & 15, l4 = lane >> 4;
    const int wv = tid >> 6;
    const size_t gT = (size_t)g * T;
    const int myTok = wv * 16 + l15;
    const float* cng = ws + WS_CNORM + (size_t)g * Q * KCODES;
    double* lpD = (double*)(ws + WS_LPARTD);
    // refinement scratch aliases CbV[0] (32 KB >= 8 waves * 1 KB; dead when
    // the fallback runs; loss-reduction __syncthreads fence next q's staging)
    float* refB = (float*)&CbV[0][0] + wv * 256;

    // LINEAR staging geometry: 4 gl_lds/thread/chunk, identity copy.
    size_t coff[4];
#pragma unroll
    for (int k = 0; k < 4; k++)
        coff[k] = (size_t)((wv * 4 + k) * 64 + lane) * 8;   // shorts

    // ---- residual (f32) lives in registers for the whole kernel ----
    float4 rA[8], rB[8];
    {
        const float* hrow = ws + WS_H + (gT + t0 + myTok) * CD + l4 * 8;
#pragma unroll
        for (int dc = 0; dc < 8; dc++) {
            rA[dc] = *(const float4*)(hrow + dc * 32);
            rB[dc] = *(const float4*)(hrow + dc * 32 + 4);
        }
    }

    for (int q = 0; q < Q; q++) {
        const float* cnq = cng + (size_t)q * KCODES;
        const double* cn64q = (const double*)(ws + WS_CN64) + ((size_t)g * Q + q) * KCODES;
        const float* cqb = cb + ((size_t)g * Q + q) * KCODES * CD;
        const short* cbtq = cbt + (size_t)(g * Q + q) * 524288;   // 32 chunks * 2048 units * 8

        cnS[tid] = cnq[tid];
        cnS[512 + tid] = cnq[512 + tid];

        // ---- split register residual to bf16 hi/lo fragments (pure VALU) ----
        s16x8 fh[8], fl[8];
#pragma unroll
        for (int dc = 0; dc < 8; dc++) {
            float v[8] = {rA[dc].x, rA[dc].y, rA[dc].z, rA[dc].w,
                          rB[dc].x, rB[dc].y, rB[dc].z, rB[dc].w};
            s16x8 th, tl;
#pragma unroll
            for (int e = 0; e < 8; e++) {
                unsigned short hb = f2bf(v[e]);
                th[e] = (short)hb;
                tl[e] = (short)f2bf(v[e] - bf2f(hb));
            }
            fh[dc] = th; fl[dc] = tl;
        }

        // stage chunk 0 into buf 0
        __syncthreads();   // CbV free (refinement alias from prev q done block-wide)
#pragma unroll
        for (int k = 0; k < 4; k++)
            gl_lds16(cbtq + coff[k], &CbV[0][(wv * 4 + k) * 64]);
        __syncthreads();   // drains vmcnt: chunk0 + cnS ready

        // top-3 values + top-2 indices (total order: value, then index)
        float tv1 = 3.4e38f, tv2 = 3.4e38f, tv3 = 3.4e38f;
        int   tix = 0x7fffffff, tix2 = 0x7fffffff;
        f32x4 acc[2];
#pragma unroll
        for (int t = 0; t < 2; t++) acc[t] = (f32x4){0.f, 0.f, 0.f, 0.f};

        for (int cc = 0; cc < 32; cc++) {
            __builtin_amdgcn_s_barrier();
            if (cc + 1 < 32) {
                const size_t add = (size_t)(cc + 1) * 16384;   // 2048 units * 8 shorts
#pragma unroll
                for (int k = 0; k < 4; k++)
                    gl_lds16(cbtq + add + coff[k], &CbV[(cc + 1) & 1][(wv * 4 + k) * 64]);
                asm volatile("s_waitcnt vmcnt(4)" ::: "memory");
            } else {
                asm volatile("s_waitcnt vmcnt(0)" ::: "memory");
            }
            __builtin_amdgcn_s_barrier();
            __builtin_amdgcn_sched_barrier(0);

            const int buf = cc & 1;
#pragma unroll
            for (int dc = 0; dc < 8; dc++) {
#pragma unroll
                for (int t = 0; t < 2; t++) {
                    int idx = dc * 128 + l4 * 32 + t * 16 + l15;
                    s16x8 ch = CbV[buf][idx];
                    s16x8 cl2 = CbV[buf][1024 + idx];
                    acc[t] = __builtin_amdgcn_mfma_f32_16x16x32_bf16(ch, fh[dc], acc[t], 0, 0, 0);
                    acc[t] = __builtin_amdgcn_mfma_f32_16x16x32_bf16(ch, fl[dc], acc[t], 0, 0, 0);
                    acc[t] = __builtin_amdgcn_mfma_f32_16x16x32_bf16(cl2, fh[dc], acc[t], 0, 0, 0);
                }
            }
            // score chunk cc (candidates arrive in ascending c within each lane)
#pragma unroll
            for (int t = 0; t < 2; t++)
#pragma unroll
                for (int r = 0; r < 4; r++) {
                    int c = cc * 32 + t * 16 + l4 * 4 + r;
                    float vv = fmaf(-2.f, acc[t][r], cnS[c]);
                    if (vv < tv1)      { tv3 = tv2; tv2 = tv1; tix2 = tix; tv1 = vv; tix = c; }
                    else if (vv < tv2) { tv3 = tv2; tv2 = vv; tix2 = c; }
                    else if (vv < tv3) { tv3 = vv; }
                }
#pragma unroll
            for (int t = 0; t < 2; t++) acc[t] = (f32x4){0.f, 0.f, 0.f, 0.f};
        }

        // ---- merge the 4 same-token lanes: sorted-triple merge (strides 16,32) ----
#pragma unroll
        for (int m = 16; m < 64; m <<= 1) {
            float b1 = __shfl_xor(tv1, m, 64);
            int   bi1 = __shfl_xor(tix, m, 64);
            float b2 = __shfl_xor(tv2, m, 64);
            int   bi2 = __shfl_xor(tix2, m, 64);
            float b3 = __shfl_xor(tv3, m, 64);
            float n1, n2, n3; int ni1, ni2;
            bool bf = (b1 < tv1) || (b1 == tv1 && bi1 < tix);
            if (bf) {
                n1 = b1; ni1 = bi1;
                bool af = (tv1 < b2) || (tv1 == b2 && tix < bi2);
                if (af) { n2 = tv1; ni2 = tix; n3 = fminf(tv2, b2); }
                else    { n2 = b2;  ni2 = bi2; n3 = fminf(tv1, b3); }
            } else {
                n1 = tv1; ni1 = tix;
                bool bs = (b1 < tv2) || (b1 == tv2 && bi1 < tix2);
                if (bs) { n2 = b1;  ni2 = bi1;  n3 = fminf(tv2, b2); }
                else    { n2 = tv2; ni2 = tix2; n3 = fminf(b1, tv3); }
            }
            tv1 = n1; tix = ni1; tv2 = n2; tix2 = ni2; tv3 = n3;
        }

        // ---- cheap exact refinement: f64 scores of top-2 only ----
        int besti = tix;
        bool flag = (tv2 - tv1 < EPS_REFINE);
        bool need_full = false;
        if (__any(flag)) {
            const float* c1r = cqb + (size_t)tix  * CD + l4 * 8;
            const float* c2r = cqb + (size_t)tix2 * CD + l4 * 8;
            double d1 = 0.0, d2 = 0.0;
#pragma unroll
            for (int dc = 0; dc < 8; dc++) {
                float4 p0 = *(const float4*)(c1r + dc * 32);
                float4 p1 = *(const float4*)(c1r + dc * 32 + 4);
                float4 q0 = *(const float4*)(c2r + dc * 32);
                float4 q1 = *(const float4*)(c2r + dc * 32 + 4);
                d1 = fma((double)rA[dc].x,(double)p0.x,d1); d1 = fma((double)rA[dc].y,(double)p0.y,d1);
                d1 = fma((double)rA[dc].z,(double)p0.z,d1); d1 = fma((double)rA[dc].w,(double)p0.w,d1);
                d1 = fma((double)rB[dc].x,(double)p1.x,d1); d1 = fma((double)rB[dc].y,(double)p1.y,d1);
                d1 = fma((double)rB[dc].z,(double)p1.z,d1); d1 = fma((double)rB[dc].w,(double)p1.w,d1);
                d2 = fma((double)rA[dc].x,(double)q0.x,d2); d2 = fma((double)rA[dc].y,(double)q0.y,d2);
                d2 = fma((double)rA[dc].z,(double)q0.z,d2); d2 = fma((double)rA[dc].w,(double)q0.w,d2);
                d2 = fma((double)rB[dc].x,(double)q1.x,d2); d2 = fma((double)rB[dc].y,(double)q1.y,d2);
                d2 = fma((double)rB[dc].z,(double)q1.z,d2); d2 = fma((double)rB[dc].w,(double)q1.w,d2);
            }
#pragma unroll
            for (int m = 16; m < 64; m <<= 1) {
                d1 += __shfl_xor(d1, m, 64);
                d2 += __shfl_xor(d2, m, 64);
            }
            double s1 = fma(-2.0, d1, cn64q[tix]);
            double s2 = fma(-2.0, d2, cn64q[tix2]);
            bool c2wins = (s2 < s1) || (s2 == s1 && tix2 < tix);
            double swin = c2wins ? s2 : s1;
            int    iwin = c2wins ? tix2 : tix;
            if (flag) besti = iwin;
            need_full = flag && !(swin < (double)tv3 - ERRB);
        }

        // ---- rare fallback: serial full f64 scan (scratch aliases CbV[0]) ----
        unsigned long long flg = __ballot(need_full) & 0xFFFFull;
        while (flg) {
            int l = __builtin_ctzll(flg); flg &= flg - 1;
            if (l15 == l) {
#pragma unroll
                for (int dc = 0; dc < 8; dc++) {
                    *(float4*)(refB + dc * 32 + l4 * 8)     = rA[dc];
                    *(float4*)(refB + dc * 32 + l4 * 8 + 4) = rB[dc];
                }
            }
            asm volatile("s_waitcnt lgkmcnt(0)" ::: "memory");
            __builtin_amdgcn_sched_barrier(0);
            const float4* rf4 = (const float4*)refB;
            double bv = 1e300; int bi = 0x7fffffff;
            for (int c = lane; c < KCODES; c += 64) {
                const float4* cp4 = (const float4*)(cqb + (size_t)c * CD);
                double a0=0, a1=0, a2=0, a3=0;
#pragma unroll 4
                for (int e = 0; e < 64; e++) {
                    float4 cv = cp4[e], rv = rf4[e];
                    a0 = fma((double)rv.x,(double)cv.x,a0); a1 = fma((double)rv.y,(double)cv.y,a1);
                    a2 = fma((double)rv.z,(double)cv.z,a2); a3 = fma((double)rv.w,(double)cv.w,a3);
                }
                double dd = fma(-2.0, (a0+a1)+(a2+a3), cn64q[c]);
                if (dd < bv) { bv = dd; bi = c; }
            }
#pragma unroll
            for (int m = 1; m < 64; m <<= 1) {
                double ov = __shfl_xor(bv, m, 64);
                int    oi = __shfl_xor(bi, m, 64);
                if (ov < bv || (ov == bv && oi < bi)) { bv = ov; bi = oi; }
            }
            if (l15 == l) besti = bi;
            asm volatile("s_waitcnt lgkmcnt(0)" ::: "memory");
        }

        // ---- idx out (lane<16 holds token wv*16+lane) ----
        if (lane < 16)
            out[OUT_IDX + (gT + t0 + wv * 16 + lane) * Q + q] = (float)besti;

        // ---- STE update in registers from gathered code row ----
        double lacc = 0.0;
        {
            const float* crow = cqb + (size_t)besti * CD + l4 * 8;
#pragma unroll
            for (int dc = 0; dc < 8; dc++) {
                float4 c0 = *(const float4*)(crow + dc * 32);
                float4 c1 = *(const float4*)(crow + dc * 32 + 4);
                STE1(rA[dc].x, c0.x); STE1(rA[dc].y, c0.y);
                STE1(rA[dc].z, c0.z); STE1(rA[dc].w, c0.w);
                STE1(rB[dc].x, c1.x); STE1(rB[dc].y, c1.y);
                STE1(rB[dc].z, c1.z); STE1(rB[dc].w, c1.w);
            }
        }
        if (q == Q - 1) {
            float* rrow = ws + WS_RES + (gT + t0 + myTok) * CD + l4 * 8;
#pragma unroll
            for (int dc = 0; dc < 8; dc++) {
                *(float4*)(rrow + dc * 32)     = rA[dc];
                *(float4*)(rrow + dc * 32 + 4) = rB[dc];
            }
        }

        // ---- deterministic loss partial (f64) ----
#pragma unroll
        for (int m = 1; m < 64; m <<= 1) lacc += __shfl_xor(lacc, m, 64);
        __syncthreads();
        if (lane == 0) lredD[wv] = lacc;
        __syncthreads();
        if (tid == 0)
            lpD[((size_t)g * Q + q) * 256 + blockIdx.x] =
                (((lredD[0] + lredD[1]) + (lredD[2] + lredD[3])) +
                 ((lredD[4] + lredD[5]) + (lredD[6] + lredD[7])));
        __syncthreads();
    }
}

// ---------------- K4: output projection out = (h - res) @ Wout_g^T + bout ----------------
__global__ __launch_bounds__(256) void k_proj_out(const float* __restrict__ ws,
                                                  const float* __restrict__ Wout,
                                                  const float* __restrict__ bout,
                                                  float* __restrict__ out) {
    __shared__ float As[32][65];
    __shared__ float Bs[32][65];
    const int g  = blockIdx.z;
    const int t0 = blockIdx.x * 64;
    const int d0 = blockIdx.y * 64;
    const int tid = threadIdx.x;
    const int tx = tid & 15, ty = tid >> 4;
    float acc[4][4] = {};
    const float* Ah = ws + WS_H + ((size_t)g * T + t0) * CD;
    const float* Ar = ws + WS_RES + ((size_t)g * T + t0) * CD;
    const float* Bb = Wout + (size_t)g * DG * CD + (size_t)d0 * CD;

    for (int k0 = 0; k0 < CD; k0 += 32) {
        __syncthreads();
#pragma unroll
        for (int j = 0; j < 8; j++) {
            int lin = j * 256 + tid;
            int k = lin & 31, r = lin >> 5;
            size_t o = (size_t)r * CD + k0 + k;
            As[k][r] = Ah[o] - Ar[o];            // qout = h - res_final
            Bs[k][r] = Bb[o];
        }
        __syncthreads();
#pragma unroll
        for (int k = 0; k < 32; k++) {
            float a[4], b[4];
#pragma unroll
            for (int i = 0; i < 4; i++) a[i] = As[k][ty + 16 * i];
#pragma unroll
            for (int j = 0; j < 4; j++) b[j] = Bs[k][tx + 16 * j];
#pragma unroll
            for (int i = 0; i < 4; i++)
#pragma unroll
                for (int j = 0; j < 4; j++) acc[i][j] = fmaf(a[i], b[j], acc[i][j]);
        }
    }
#pragma unroll
    for (int i = 0; i < 4; i++) {
        int t = t0 + ty + 16 * i;
#pragma unroll
        for (int j = 0; j < 4; j++) {
            int d = d0 + tx + 16 * j;
            out[(size_t)t * DIMV + (size_t)g * DG + d] = acc[i][j] + bout[g * DG + d];
        }
    }
}

// ---------------- K5: deterministic loss reduction (f64 -> f32) ----------------
__global__ void k_loss(const float* __restrict__ ws, float* __restrict__ out) {
    int gq = blockIdx.x;
    const double* lpD = (const double*)(ws + WS_LPARTD);
    double v = lpD[(size_t)gq * 256 + threadIdx.x];
#pragma unroll
    for (int m = 1; m < 64; m <<= 1) v += __shfl_xor(v, m, 64);
    __shared__ double red[4];
    if ((threadIdx.x & 63) == 0) red[threadIdx.x >> 6] = v;
    __syncthreads();
    if (threadIdx.x == 0)
        out[OUT_LOSS + gq] =
            (float)(((red[0] + red[1]) + (red[2] + red[3])) * (1.0 / 8388608.0));
}

extern "C" void kernel_launch(void* const* d_in, const int* in_sizes, int n_in,
                              void* d_out, int out_size, void* d_ws, size_t ws_size,
                              hipStream_t stream) {
    const float* x    = (const float*)d_in[0];
    const float* Win  = (const float*)d_in[1];
    const float* bin  = (const float*)d_in[2];
    const float* Wout = (const float*)d_in[3];
    const float* bout = (const float*)d_in[4];
    const float* cb   = (const float*)d_in[5];
    float* out = (float*)d_out;
    float* ws  = (float*)d_ws;

    // Pre-transposed bf16 hi/lo codebook in the not-yet-written quantized
    // region of d_out: G*Q*K*CD*2 planes = 8.4M shorts = 4.2M f32-equiv
    // << 41.9M f32 region (k_proj_out overwrites the region at the end).
    short* cbt = (short*)d_out;

    hipLaunchKernelGGL(k_norms,    dim3(64),          dim3(256), 0, stream, cb, ws);
    hipLaunchKernelGGL(k_split,    dim3(2048),        dim3(256), 0, stream, cb, cbt);
    hipLaunchKernelGGL(k_proj_in,  dim3(T/64, 4, G),  dim3(256), 0, stream, x, Win, bin, ws);
    hipLaunchKernelGGL(k_rvq,      dim3(T/TM, G),     dim3(512), 0, stream, cb, ws, out, cbt);
    hipLaunchKernelGGL(k_proj_out, dim3(T/64, 10, G), dim3(256), 0, stream, ws, Wout, bout, out);
    hipLaunchKernelGGL(k_loss,     dim3(16),          dim3(256), 0, stream, ws, out);
}

// Round 19
// 1850.180 us; speedup vs baseline: 1.0838x; 1.0838x over previous
//
#include <hip/hip_runtime.h>
#include <hip/hip_bf16.h>

// Grouped Residual VQ: G=2, Q=8, K=1024, CD=256, DIM=1280 (DG=640), T=32768.
//
// Round 19: DOUBLE B-OPERAND REUSE. 4 waves/block, each wave owns 32 tokens
// (2 register fragment sets, 128 VGPR) -> each codebook LDS read feeds 6
// MFMAs (was 3), halving the LDS-read traffic per token that walled r18.
// Residual state moves back to global (epilogue: read rsrc -> STE -> write
// rbuf -> rebuild fragments in-register for next q). Codebook staging is the
// r16-verified linear copy of the pre-transposed scratch (0 conflicts).

#define G 2
#define Q 8
#define KCODES 1024
#define CD 256
#define DIMV 1280
#define DG 640
#define T 32768
#define TM 128

#define WS_H      ((size_t)0)
#define WS_RES    (WS_H + (size_t)G*T*CD)
#define WS_CNORM  (WS_RES + (size_t)G*T*CD)
#define WS_CN64   (WS_CNORM + (size_t)G*Q*KCODES)
#define WS_LPARTD (WS_CN64 + (size_t)2*G*Q*KCODES)

#define OUT_IDX   ((size_t)T*DIMV)
#define OUT_LOSS  (OUT_IDX + (size_t)G*T*Q)

#define EPS_REFINE 2e-3f
#define ERRB 1e-3

typedef __attribute__((ext_vector_type(8))) short s16x8;
typedef __attribute__((ext_vector_type(4))) float f32x4;

static __device__ __forceinline__ unsigned short f2bf(float v) {
    __hip_bfloat16 b = __float2bfloat16(v);
    return *(unsigned short*)&b;
}
static __device__ __forceinline__ float bf2f(unsigned short u) {
    __hip_bfloat16 b = *(__hip_bfloat16*)&u;
    return __bfloat162float(b);
}

static __device__ __forceinline__ void gl_lds16(const void* g, void* l) {
    __builtin_amdgcn_global_load_lds(
        (const __attribute__((address_space(1))) unsigned int*)g,
        (__attribute__((address_space(3))) unsigned int*)l, 16, 0, 0);
}

__device__ __forceinline__ float np_half_sumsq(const float4* __restrict__ p) {
    float4 a = p[0], b = p[1];
    float r0=a.x*a.x, r1=a.y*a.y, r2=a.z*a.z, r3=a.w*a.w;
    float r4=b.x*b.x, r5=b.y*b.y, r6=b.z*b.z, r7=b.w*b.w;
#pragma unroll
    for (int i = 1; i < 16; i++) {
        a = p[2*i]; b = p[2*i+1];
        r0 += a.x*a.x; r1 += a.y*a.y; r2 += a.z*a.z; r3 += a.w*a.w;
        r4 += b.x*b.x; r5 += b.y*b.y; r6 += b.z*b.z; r7 += b.w*b.w;
    }
    return ((r0+r1)+(r2+r3)) + ((r4+r5)+(r6+r7));
}

// ---------------- K1: codebook norms (f32 + exact f64) ----------------
__global__ void k_norms(const float* __restrict__ cb, float* __restrict__ ws) {
    int r = blockIdx.x * 256 + threadIdx.x;
    const float4* row = (const float4*)(cb + (size_t)r * CD);
    ws[WS_CNORM + r] = np_half_sumsq(row) + np_half_sumsq(row + 32);
    double s0=0, s1=0, s2=0, s3=0;
#pragma unroll 8
    for (int e = 0; e < 64; e++) {
        float4 v = row[e];
        s0 = fma((double)v.x,(double)v.x,s0); s1 = fma((double)v.y,(double)v.y,s1);
        s2 = fma((double)v.z,(double)v.z,s2); s3 = fma((double)v.w,(double)v.w,s3);
    }
    ((double*)(ws + WS_CN64))[r] = (s0+s1)+(s2+s3);
}

// ---------------- K1b: codebook bf16 hi/lo split + LDS-order transpose ----------------
// cbt unit order: [(gq*32+cc32)*2+pl][dc 8][ku 4][code32 32] (16B units).
__global__ void k_split(const float* __restrict__ cb, short* __restrict__ cbt) {
    int tau = blockIdx.x * 256 + threadIdx.x;     // 0 .. G*Q*KCODES*32-1
    int u = tau & 31;                             // dim unit within row
    int row = tau >> 5;                           // global code row 0..G*Q*K-1
    int gq = row >> 10;
    int code = row & 1023;
    int cc = code >> 5, c32 = code & 31;
    const float* src = cb + (size_t)row * CD + u * 8;
    float4 v0 = *(const float4*)src;
    float4 v1 = *(const float4*)(src + 4);
    float v[8] = {v0.x,v0.y,v0.z,v0.w,v1.x,v1.y,v1.z,v1.w};
    s16x8 hh, ll;
#pragma unroll
    for (int e = 0; e < 8; e++) {
        unsigned short hb = f2bf(v[e]);
        hh[e] = (short)hb;
        ll[e] = (short)f2bf(v[e] - bf2f(hb));
    }
    int n = (u >> 2) * 128 + (u & 3) * 32 + c32;  // dc*128 + ku*32 + code32
    size_t base = ((size_t)(gq * 32 + cc) * 2) * 1024;
    *(s16x8*)(cbt + (base + n) * 8)        = hh;  // plane 0 (hi)
    *(s16x8*)(cbt + (base + 1024 + n) * 8) = ll;  // plane 1 (lo)
}

// ---------------- K2: input projection h = x_g @ Win_g^T + bin ----------------
__global__ __launch_bounds__(256) void k_proj_in(const float* __restrict__ x,
                                                 const float* __restrict__ Win,
                                                 const float* __restrict__ bin,
                                                 float* __restrict__ ws) {
    __shared__ float As[32][65];
    __shared__ float Bs[32][65];
    const int g  = blockIdx.z;
    const int t0 = blockIdx.x * 64;
    const int c0 = blockIdx.y * 64;
    const int tid = threadIdx.x;
    const int tx = tid & 15, ty = tid >> 4;
    float acc[4][4] = {};
    const float* Ab = x + (size_t)t0 * DIMV + (size_t)g * DG;
    const float* Bb = Win + (size_t)g * CD * DG + (size_t)c0 * DG;

    for (int k0 = 0; k0 < DG; k0 += 32) {
        __syncthreads();
#pragma unroll
        for (int j = 0; j < 8; j++) {
            int lin = j * 256 + tid;
            int k = lin & 31, r = lin >> 5;
            As[k][r] = Ab[(size_t)r * DIMV + k0 + k];
            Bs[k][r] = Bb[(size_t)r * DG + k0 + k];
        }
        __syncthreads();
#pragma unroll
        for (int k = 0; k < 32; k++) {
            float a[4], b[4];
#pragma unroll
            for (int i = 0; i < 4; i++) a[i] = As[k][ty + 16 * i];
#pragma unroll
            for (int j = 0; j < 4; j++) b[j] = Bs[k][tx + 16 * j];
#pragma unroll
            for (int i = 0; i < 4; i++)
#pragma unroll
                for (int j = 0; j < 4; j++) acc[i][j] = fmaf(a[i], b[j], acc[i][j]);
        }
    }
#pragma unroll
    for (int i = 0; i < 4; i++) {
        int t = t0 + ty + 16 * i;
        float* hrow = ws + WS_H + ((size_t)g * T + t) * CD;
#pragma unroll
        for (int j = 0; j < 4; j++) {
            int c = c0 + tx + 16 * j;
            hrow[c] = acc[i][j] + bin[g * CD + c];
        }
    }
}

// ---------------- K3: fused ResidualVQ (2 frag sets/wave, 4 waves) ----------------
#define STE1F(rv, cv) { float tt_ = __fsub_rn((cv), (rv)); float qq_ = __fadd_rn((rv), tt_); \
                        float rr_ = __fsub_rn((rv), qq_); lacc += (double)rr_ * rr_; (rv) = rr_; }

__global__ __launch_bounds__(256, 2) void k_rvq(const float* __restrict__ cb,
                                                float* __restrict__ ws,
                                                float* __restrict__ out,
                                                const short* __restrict__ cbt) {
    __shared__ s16x8 CbV[2][2048];               // 64 KB: [pl 2][dc 8][ku 4][code32 32] x2
    __shared__ float cnS[KCODES];                // 4 KB
    __shared__ double lredD[4];

    const int g  = blockIdx.y;
    const int t0 = blockIdx.x * TM;
    const int tid = threadIdx.x;
    const int lane = tid & 63, l15 = lane & 15, l4 = lane >> 4;
    const int wv = tid >> 6;                     // 0..3
    const size_t gT = (size_t)g * T;
    const float* cng = ws + WS_CNORM + (size_t)g * Q * KCODES;
    float* hbuf = ws + WS_H;
    float* rbuf = ws + WS_RES;
    double* lpD = (double*)(ws + WS_LPARTD);

    // LINEAR staging geometry: 8 gl_lds/thread/chunk, identity copy.
    int coff[8];
#pragma unroll
    for (int k = 0; k < 8; k++)
        coff[k] = ((wv * 8 + k) * 64 + lane) * 8;   // shorts

    // ---- fragments for 2 token sets (token = wv*32 + s*16 + l15) ----
    s16x8 fh[2][8], fl[2][8];
#pragma unroll
    for (int s = 0; s < 2; s++) {
        const float* hrow = hbuf + (gT + t0 + wv * 32 + s * 16 + l15) * CD + l4 * 8;
#pragma unroll
        for (int dc = 0; dc < 8; dc++) {
            float4 u0 = *(const float4*)(hrow + dc * 32);
            float4 u1 = *(const float4*)(hrow + dc * 32 + 4);
            float v[8] = {u0.x,u0.y,u0.z,u0.w,u1.x,u1.y,u1.z,u1.w};
            s16x8 th, tl;
#pragma unroll
            for (int e = 0; e < 8; e++) {
                unsigned short hb = f2bf(v[e]);
                th[e] = (short)hb;
                tl[e] = (short)f2bf(v[e] - bf2f(hb));
            }
            fh[s][dc] = th; fl[s][dc] = tl;
        }
    }

    for (int q = 0; q < Q; q++) {
        const float* cnq = cng + (size_t)q * KCODES;
        const double* cn64q = (const double*)(ws + WS_CN64) + ((size_t)g * Q + q) * KCODES;
        const float* cqb = cb + ((size_t)g * Q + q) * KCODES * CD;
        const short* cbtq = cbt + (size_t)(g * Q + q) * 524288;   // 32 chunks * 2048 units * 8
        const float* rsrc = (q == 0) ? hbuf : rbuf;

#pragma unroll
        for (int i = 0; i < 4; i++) cnS[i * 256 + tid] = cnq[i * 256 + tid];

        // stage chunk 0 into buf 0
#pragma unroll
        for (int k = 0; k < 8; k++)
            gl_lds16(cbtq + coff[k], &CbV[0][(wv * 8 + k) * 64]);
        __syncthreads();   // drains vmcnt: chunk0 + cnS ready

        // per-set top-3 values + top-2 indices (total order: value, then index)
        float tv1[2] = {3.4e38f, 3.4e38f}, tv2[2] = {3.4e38f, 3.4e38f}, tv3[2] = {3.4e38f, 3.4e38f};
        int   tix[2] = {0x7fffffff, 0x7fffffff}, tix2[2] = {0x7fffffff, 0x7fffffff};
        f32x4 acc[2][2];
#pragma unroll
        for (int s = 0; s < 2; s++)
#pragma unroll
            for (int t = 0; t < 2; t++) acc[s][t] = (f32x4){0.f, 0.f, 0.f, 0.f};

        for (int cc = 0; cc < 32; cc++) {
            __builtin_amdgcn_s_barrier();
            if (cc + 1 < 32) {
                const int add = (cc + 1) * 16384;     // 2048 units * 8 shorts
#pragma unroll
                for (int k = 0; k < 8; k++)
                    gl_lds16(cbtq + add + coff[k], &CbV[(cc + 1) & 1][(wv * 8 + k) * 64]);
                asm volatile("s_waitcnt vmcnt(8)" ::: "memory");
            } else {
                asm volatile("s_waitcnt vmcnt(0)" ::: "memory");
            }
            __builtin_amdgcn_s_barrier();
            __builtin_amdgcn_sched_barrier(0);

            const int buf = cc & 1;
#pragma unroll
            for (int dc = 0; dc < 8; dc++) {
#pragma unroll
                for (int t = 0; t < 2; t++) {
                    int idx = dc * 128 + l4 * 32 + t * 16 + l15;
                    s16x8 ch = CbV[buf][idx];
                    s16x8 cl2 = CbV[buf][1024 + idx];
#pragma unroll
                    for (int s = 0; s < 2; s++) {
                        acc[s][t] = __builtin_amdgcn_mfma_f32_16x16x32_bf16(ch, fh[s][dc], acc[s][t], 0, 0, 0);
                        acc[s][t] = __builtin_amdgcn_mfma_f32_16x16x32_bf16(ch, fl[s][dc], acc[s][t], 0, 0, 0);
                        acc[s][t] = __builtin_amdgcn_mfma_f32_16x16x32_bf16(cl2, fh[s][dc], acc[s][t], 0, 0, 0);
                    }
                }
            }
            // score chunk cc (candidates arrive in ascending c within each lane)
#pragma unroll
            for (int s = 0; s < 2; s++)
#pragma unroll
                for (int t = 0; t < 2; t++)
#pragma unroll
                    for (int r = 0; r < 4; r++) {
                        int c = cc * 32 + t * 16 + l4 * 4 + r;
                        float vv = fmaf(-2.f, acc[s][t][r], cnS[c]);
                        if (vv < tv1[s])      { tv3[s] = tv2[s]; tv2[s] = tv1[s]; tix2[s] = tix[s]; tv1[s] = vv; tix[s] = c; }
                        else if (vv < tv2[s]) { tv3[s] = tv2[s]; tv2[s] = vv; tix2[s] = c; }
                        else if (vv < tv3[s]) { tv3[s] = vv; }
                    }
#pragma unroll
            for (int s = 0; s < 2; s++)
#pragma unroll
                for (int t = 0; t < 2; t++) acc[s][t] = (f32x4){0.f, 0.f, 0.f, 0.f};
        }

        // ---- merge the 4 same-token lanes (strides 16,32) per set ----
#pragma unroll
        for (int s = 0; s < 2; s++) {
#pragma unroll
            for (int m = 16; m < 64; m <<= 1) {
                float b1 = __shfl_xor(tv1[s], m, 64);
                int   bi1 = __shfl_xor(tix[s], m, 64);
                float b2 = __shfl_xor(tv2[s], m, 64);
                int   bi2 = __shfl_xor(tix2[s], m, 64);
                float b3 = __shfl_xor(tv3[s], m, 64);
                float n1, n2, n3; int ni1, ni2;
                bool bf = (b1 < tv1[s]) || (b1 == tv1[s] && bi1 < tix[s]);
                if (bf) {
                    n1 = b1; ni1 = bi1;
                    bool af = (tv1[s] < b2) || (tv1[s] == b2 && tix[s] < bi2);
                    if (af) { n2 = tv1[s]; ni2 = tix[s]; n3 = fminf(tv2[s], b2); }
                    else    { n2 = b2;     ni2 = bi2;    n3 = fminf(tv1[s], b3); }
                } else {
                    n1 = tv1[s]; ni1 = tix[s];
                    bool bs = (b1 < tv2[s]) || (b1 == tv2[s] && bi1 < tix2[s]);
                    if (bs) { n2 = b1;     ni2 = bi1;     n3 = fminf(tv2[s], b2); }
                    else    { n2 = tv2[s]; ni2 = tix2[s]; n3 = fminf(b1, tv3[s]); }
                }
                tv1[s] = n1; tix[s] = ni1; tv2[s] = n2; tix2[s] = ni2; tv3[s] = n3;
            }
        }

        // ---- cheap exact refinement per set: f64 scores of top-2 only ----
        int besti[2];
        bool need_full[2];
#pragma unroll 1
        for (int s = 0; s < 2; s++) {
            besti[s] = tix[s];
            need_full[s] = false;
            bool flag = (tv2[s] - tv1[s] < EPS_REFINE);
            if (!__any(flag)) continue;
            const float* rrow = rsrc + (gT + t0 + wv * 32 + s * 16 + l15) * CD + l4 * 8;
            const float* c1r = cqb + (size_t)tix[s]  * CD + l4 * 8;
            const float* c2r = cqb + (size_t)tix2[s] * CD + l4 * 8;
            double d1 = 0.0, d2 = 0.0;
#pragma unroll
            for (int dc = 0; dc < 8; dc++) {
                float4 r0 = *(const float4*)(rrow + dc * 32);
                float4 r1 = *(const float4*)(rrow + dc * 32 + 4);
                float4 p0 = *(const float4*)(c1r + dc * 32);
                float4 p1 = *(const float4*)(c1r + dc * 32 + 4);
                float4 q0 = *(const float4*)(c2r + dc * 32);
                float4 q1 = *(const float4*)(c2r + dc * 32 + 4);
                d1 = fma((double)r0.x,(double)p0.x,d1); d1 = fma((double)r0.y,(double)p0.y,d1);
                d1 = fma((double)r0.z,(double)p0.z,d1); d1 = fma((double)r0.w,(double)p0.w,d1);
                d1 = fma((double)r1.x,(double)p1.x,d1); d1 = fma((double)r1.y,(double)p1.y,d1);
                d1 = fma((double)r1.z,(double)p1.z,d1); d1 = fma((double)r1.w,(double)p1.w,d1);
                d2 = fma((double)r0.x,(double)q0.x,d2); d2 = fma((double)r0.y,(double)q0.y,d2);
                d2 = fma((double)r0.z,(double)q0.z,d2); d2 = fma((double)r0.w,(double)q0.w,d2);
                d2 = fma((double)r1.x,(double)q1.x,d2); d2 = fma((double)r1.y,(double)q1.y,d2);
                d2 = fma((double)r1.z,(double)q1.z,d2); d2 = fma((double)r1.w,(double)q1.w,d2);
            }
#pragma unroll
            for (int m = 16; m < 64; m <<= 1) {
                d1 += __shfl_xor(d1, m, 64);
                d2 += __shfl_xor(d2, m, 64);
            }
            double s1 = fma(-2.0, d1, cn64q[tix[s]]);
            double s2 = fma(-2.0, d2, cn64q[tix2[s]]);
            bool c2wins = (s2 < s1) || (s2 == s1 && tix2[s] < tix[s]);
            double swin = c2wins ? s2 : s1;
            int    iwin = c2wins ? tix2[s] : tix[s];
            if (flag) besti[s] = iwin;
            need_full[s] = flag && !(swin < (double)tv3[s] - ERRB);
        }

        // ---- rare fallback: serial full f64 scan (reads rsrc from global) ----
#pragma unroll 1
        for (int s = 0; s < 2; s++) {
            unsigned long long flg = __ballot(need_full[s]) & 0xFFFFull;
            while (flg) {
                int l = __builtin_ctzll(flg); flg &= flg - 1;
                const float4* rf4 = (const float4*)(rsrc + (gT + t0 + wv * 32 + s * 16 + l) * CD);
                double bv = 1e300; int bi = 0x7fffffff;
                for (int c = lane; c < KCODES; c += 64) {
                    const float4* cp4 = (const float4*)(cqb + (size_t)c * CD);
                    double a0=0, a1=0, a2=0, a3=0;
#pragma unroll 4
                    for (int e = 0; e < 64; e++) {
                        float4 cv = cp4[e], rv = rf4[e];
                        a0 = fma((double)rv.x,(double)cv.x,a0); a1 = fma((double)rv.y,(double)cv.y,a1);
                        a2 = fma((double)rv.z,(double)cv.z,a2); a3 = fma((double)rv.w,(double)cv.w,a3);
                    }
                    double dd = fma(-2.0, (a0+a1)+(a2+a3), cn64q[c]);
                    if (dd < bv) { bv = dd; bi = c; }
                }
#pragma unroll
                for (int m = 1; m < 64; m <<= 1) {
                    double ov = __shfl_xor(bv, m, 64);
                    int    oi = __shfl_xor(bi, m, 64);
                    if (ov < bv || (ov == bv && oi < bi)) { bv = ov; bi = oi; }
                }
                if (l15 == l) besti[s] = bi;
            }
        }

        // ---- idx out (l4==0 lane per (s, l15)) ----
        if (lane < 16) {
#pragma unroll
            for (int s = 0; s < 2; s++)
                out[OUT_IDX + (gT + t0 + wv * 32 + s * 16 + lane) * Q + q] = (float)besti[s];
        }

        // ---- STE epilogue: read rsrc, update, write rbuf, rebuild frags ----
        double lacc = 0.0;
#pragma unroll
        for (int s = 0; s < 2; s++) {
            size_t off = (gT + t0 + wv * 32 + s * 16 + l15) * CD + l4 * 8;
            const float* rp = rsrc + off;
            const float* crow = cqb + (size_t)besti[s] * CD + l4 * 8;
            float* wp = rbuf + off;
#pragma unroll
            for (int dc = 0; dc < 8; dc++) {
                float4 r0 = *(const float4*)(rp + dc * 32);
                float4 r1 = *(const float4*)(rp + dc * 32 + 4);
                float4 c0 = *(const float4*)(crow + dc * 32);
                float4 c1 = *(const float4*)(crow + dc * 32 + 4);
                STE1F(r0.x, c0.x); STE1F(r0.y, c0.y); STE1F(r0.z, c0.z); STE1F(r0.w, c0.w);
                STE1F(r1.x, c1.x); STE1F(r1.y, c1.y); STE1F(r1.z, c1.z); STE1F(r1.w, c1.w);
                *(float4*)(wp + dc * 32)     = r0;
                *(float4*)(wp + dc * 32 + 4) = r1;
                float v[8] = {r0.x,r0.y,r0.z,r0.w,r1.x,r1.y,r1.z,r1.w};
                s16x8 th, tl;
#pragma unroll
                for (int e = 0; e < 8; e++) {
                    unsigned short hb = f2bf(v[e]);
                    th[e] = (short)hb;
                    tl[e] = (short)f2bf(v[e] - bf2f(hb));
                }
                fh[s][dc] = th; fl[s][dc] = tl;
            }
        }

        // ---- deterministic loss partial (f64) ----
#pragma unroll
        for (int m = 1; m < 64; m <<= 1) lacc += __shfl_xor(lacc, m, 64);
        __syncthreads();
        if (lane == 0) lredD[wv] = lacc;
        __syncthreads();
        if (tid == 0)
            lpD[((size_t)g * Q + q) * 256 + blockIdx.x] =
                ((lredD[0] + lredD[1]) + (lredD[2] + lredD[3]));
        __syncthreads();   // vmcnt drained: rbuf writes visible before next q
    }
}

// ---------------- K4: output projection out = (h - res) @ Wout_g^T + bout ----------------
__global__ __launch_bounds__(256) void k_proj_out(const float* __restrict__ ws,
                                                  const float* __restrict__ Wout,
                                                  const float* __restrict__ bout,
                                                  float* __restrict__ out) {
    __shared__ float As[32][65];
    __shared__ float Bs[32][65];
    const int g  = blockIdx.z;
    const int t0 = blockIdx.x * 64;
    const int d0 = blockIdx.y * 64;
    const int tid = threadIdx.x;
    const int tx = tid & 15, ty = tid >> 4;
    float acc[4][4] = {};
    const float* Ah = ws + WS_H + ((size_t)g * T + t0) * CD;
    const float* Ar = ws + WS_RES + ((size_t)g * T + t0) * CD;
    const float* Bb = Wout + (size_t)g * DG * CD + (size_t)d0 * CD;

    for (int k0 = 0; k0 < CD; k0 += 32) {
        __syncthreads();
#pragma unroll
        for (int j = 0; j < 8; j++) {
            int lin = j * 256 + tid;
            int k = lin & 31, r = lin >> 5;
            size_t o = (size_t)r * CD + k0 + k;
            As[k][r] = Ah[o] - Ar[o];            // qout = h - res_final
            Bs[k][r] = Bb[o];
        }
        __syncthreads();
#pragma unroll
        for (int k = 0; k < 32; k++) {
            float a[4], b[4];
#pragma unroll
            for (int i = 0; i < 4; i++) a[i] = As[k][ty + 16 * i];
#pragma unroll
            for (int j = 0; j < 4; j++) b[j] = Bs[k][tx + 16 * j];
#pragma unroll
            for (int i = 0; i < 4; i++)
#pragma unroll
                for (int j = 0; j < 4; j++) acc[i][j] = fmaf(a[i], b[j], acc[i][j]);
        }
    }
#pragma unroll
    for (int i = 0; i < 4; i++) {
        int t = t0 + ty + 16 * i;
#pragma unroll
        for (int j = 0; j < 4; j++) {
            int d = d0 + tx + 16 * j;
            out[(size_t)t * DIMV + (size_t)g * DG + d] = acc[i][j] + bout[g * DG + d];
        }
    }
}

// ---------------- K5: deterministic loss reduction (f64 -> f32) ----------------
__global__ void k_loss(const float* __restrict__ ws, float* __restrict__ out) {
    int gq = blockIdx.x;
    const double* lpD = (const double*)(ws + WS_LPARTD);
    double v = lpD[(size_t)gq * 256 + threadIdx.x];
#pragma unroll
    for (int m = 1; m < 64; m <<= 1) v += __shfl_xor(v, m, 64);
    __shared__ double red[4];
    if ((threadIdx.x & 63) == 0) red[threadIdx.x >> 6] = v;
    __syncthreads();
    if (threadIdx.x == 0)
        out[OUT_LOSS + gq] =
            (float)(((red[0] + red[1]) + (red[2] + red[3])) * (1.0 / 8388608.0));
}

extern "C" void kernel_launch(void* const* d_in, const int* in_sizes, int n_in,
                              void* d_out, int out_size, void* d_ws, size_t ws_size,
                              hipStream_t stream) {
    const float* x    = (const float*)d_in[0];
    const float* Win  = (const float*)d_in[1];
    const float* bin  = (const float*)d_in[2];
    const float* Wout = (const float*)d_in[3];
    const float* bout = (const float*)d_in[4];
    const float* cb   = (const float*)d_in[5];
    float* out = (float*)d_out;
    float* ws  = (float*)d_ws;

    // Pre-transposed bf16 hi/lo codebook in the not-yet-written quantized
    // region of d_out: 8.4M shorts = 4.2M f32-equiv << 41.9M f32 region.
    short* cbt = (short*)d_out;

    hipLaunchKernelGGL(k_norms,    dim3(64),          dim3(256), 0, stream, cb, ws);
    hipLaunchKernelGGL(k_split,    dim3(2048),        dim3(256), 0, stream, cb, cbt);
    hipLaunchKernelGGL(k_proj_in,  dim3(T/64, 4, G),  dim3(256), 0, stream, x, Win, bin, ws);
    hipLaunchKernelGGL(k_rvq,      dim3(T/TM, G),     dim3(256), 0, stream, cb, ws, out, cbt);
    hipLaunchKernelGGL(k_proj_out, dim3(T/64, 10, G), dim3(256), 0, stream, ws, Wout, bout, out);
    hipLaunchKernelGGL(k_loss,     dim3(16),          dim3(256), 0, stream, ws, out);
}

// Round 21
// 1476.890 us; speedup vs baseline: 1.3578x; 1.2528x over previous
//
#include <hip/hip_runtime.h>
#include <hip/hip_bf16.h>

// Grouped Residual VQ: G=2, Q=8, K=1024, CD=256, DIM=1280 (DG=640), T=32768.
//
// Round 21 = r20 with the projection fragment reads FIXED: each wave now
// reads its own sub-tile rows/cols (wty*32 / wtx*32 offsets were missing ->
// all waves computed the top-left 32x32 block; h was garbage for 3/4 of
// entries). k_rvq/k_norms/k_split/k_loss byte-identical to passing r19.

#define G 2
#define Q 8
#define KCODES 1024
#define CD 256
#define DIMV 1280
#define DG 640
#define T 32768
#define TM 128

#define WS_H      ((size_t)0)
#define WS_RES    (WS_H + (size_t)G*T*CD)
#define WS_CNORM  (WS_RES + (size_t)G*T*CD)
#define WS_CN64   (WS_CNORM + (size_t)G*Q*KCODES)
#define WS_LPARTD (WS_CN64 + (size_t)2*G*Q*KCODES)

#define OUT_IDX   ((size_t)T*DIMV)
#define OUT_LOSS  (OUT_IDX + (size_t)G*T*Q)

#define EPS_REFINE 2e-3f
#define ERRB 1e-3

typedef __attribute__((ext_vector_type(8))) short s16x8;
typedef __attribute__((ext_vector_type(4))) float f32x4;

static __device__ __forceinline__ unsigned short f2bf(float v) {
    __hip_bfloat16 b = __float2bfloat16(v);
    return *(unsigned short*)&b;
}
static __device__ __forceinline__ float bf2f(unsigned short u) {
    __hip_bfloat16 b = *(__hip_bfloat16*)&u;
    return __bfloat162float(b);
}

static __device__ __forceinline__ void gl_lds16(const void* g, void* l) {
    __builtin_amdgcn_global_load_lds(
        (const __attribute__((address_space(1))) unsigned int*)g,
        (__attribute__((address_space(3))) unsigned int*)l, 16, 0, 0);
}

__device__ __forceinline__ float np_half_sumsq(const float4* __restrict__ p) {
    float4 a = p[0], b = p[1];
    float r0=a.x*a.x, r1=a.y*a.y, r2=a.z*a.z, r3=a.w*a.w;
    float r4=b.x*b.x, r5=b.y*b.y, r6=b.z*b.z, r7=b.w*b.w;
#pragma unroll
    for (int i = 1; i < 16; i++) {
        a = p[2*i]; b = p[2*i+1];
        r0 += a.x*a.x; r1 += a.y*a.y; r2 += a.z*a.z; r3 += a.w*a.w;
        r4 += b.x*b.x; r5 += b.y*b.y; r6 += b.z*b.z; r7 += b.w*b.w;
    }
    return ((r0+r1)+(r2+r3)) + ((r4+r5)+(r6+r7));
}

// ---------------- K1: codebook norms (f32 + exact f64) ----------------
__global__ void k_norms(const float* __restrict__ cb, float* __restrict__ ws) {
    int r = blockIdx.x * 256 + threadIdx.x;
    const float4* row = (const float4*)(cb + (size_t)r * CD);
    ws[WS_CNORM + r] = np_half_sumsq(row) + np_half_sumsq(row + 32);
    double s0=0, s1=0, s2=0, s3=0;
#pragma unroll 8
    for (int e = 0; e < 64; e++) {
        float4 v = row[e];
        s0 = fma((double)v.x,(double)v.x,s0); s1 = fma((double)v.y,(double)v.y,s1);
        s2 = fma((double)v.z,(double)v.z,s2); s3 = fma((double)v.w,(double)v.w,s3);
    }
    ((double*)(ws + WS_CN64))[r] = (s0+s1)+(s2+s3);
}

// ---------------- K1b: codebook bf16 hi/lo split + LDS-order transpose ----------------
__global__ void k_split(const float* __restrict__ cb, short* __restrict__ cbt) {
    int tau = blockIdx.x * 256 + threadIdx.x;
    int u = tau & 31;
    int row = tau >> 5;
    int gq = row >> 10;
    int code = row & 1023;
    int cc = code >> 5, c32 = code & 31;
    const float* src = cb + (size_t)row * CD + u * 8;
    float4 v0 = *(const float4*)src;
    float4 v1 = *(const float4*)(src + 4);
    float v[8] = {v0.x,v0.y,v0.z,v0.w,v1.x,v1.y,v1.z,v1.w};
    s16x8 hh, ll;
#pragma unroll
    for (int e = 0; e < 8; e++) {
        unsigned short hb = f2bf(v[e]);
        hh[e] = (short)hb;
        ll[e] = (short)f2bf(v[e] - bf2f(hb));
    }
    int n = (u >> 2) * 128 + (u & 3) * 32 + c32;
    size_t base = ((size_t)(gq * 32 + cc) * 2) * 1024;
    *(s16x8*)(cbt + (base + n) * 8)        = hh;
    *(s16x8*)(cbt + (base + 1024 + n) * 8) = ll;
}

// ---------------- K2: input projection h = x_g @ Win_g^T + bin (6-product MFMA) ----------------
__global__ __launch_bounds__(256) void k_proj_in(const float* __restrict__ x,
                                                 const float* __restrict__ Win,
                                                 const float* __restrict__ bin,
                                                 float* __restrict__ ws) {
    __shared__ s16x8 As[780];    // 3 planes * 4 ku * 65
    __shared__ s16x8 Bs[780];
    const int g  = blockIdx.z;
    const int t0 = blockIdx.x * 64;
    const int c0 = blockIdx.y * 64;
    const int tid = threadIdx.x;
    const int lane = tid & 63, l15 = lane & 15, l4 = lane >> 4;
    const int wv = tid >> 6, wty = wv >> 1, wtx = wv & 1;
    const int srow = tid >> 2, sku = tid & 3;     // staging: row, k-unit
    const float* Ag = x + (size_t)g * DG;
    const float* Bg = Win + (size_t)g * CD * DG;
    float* hbuf = ws + WS_H + (size_t)g * T * CD;

    f32x4 acc[2][2];
#pragma unroll
    for (int i = 0; i < 2; i++)
#pragma unroll
        for (int j = 0; j < 2; j++) acc[i][j] = (f32x4){0.f,0.f,0.f,0.f};

    for (int k0 = 0; k0 < DG; k0 += 32) {
        const float* ap = Ag + (size_t)(t0 + srow) * DIMV + k0 + sku * 8;
        const float* bp = Bg + (size_t)(c0 + srow) * DG + k0 + sku * 8;
        float4 a0 = *(const float4*)ap, a1 = *(const float4*)(ap + 4);
        float4 b0 = *(const float4*)bp, b1 = *(const float4*)(bp + 4);
        __syncthreads();
        {
            float va[8] = {a0.x,a0.y,a0.z,a0.w,a1.x,a1.y,a1.z,a1.w};
            float vb[8] = {b0.x,b0.y,b0.z,b0.w,b1.x,b1.y,b1.z,b1.w};
            s16x8 pa[3], pb[3];
#pragma unroll
            for (int e = 0; e < 8; e++) {
                float v = va[e];
                unsigned short q1 = f2bf(v); float r1 = v - bf2f(q1);
                unsigned short q2 = f2bf(r1); float r2 = r1 - bf2f(q2);
                pa[0][e] = (short)q1; pa[1][e] = (short)q2; pa[2][e] = (short)f2bf(r2);
                v = vb[e];
                q1 = f2bf(v); r1 = v - bf2f(q1);
                q2 = f2bf(r1); r2 = r1 - bf2f(q2);
                pb[0][e] = (short)q1; pb[1][e] = (short)q2; pb[2][e] = (short)f2bf(r2);
            }
#pragma unroll
            for (int pl = 0; pl < 3; pl++) {
                As[pl * 260 + sku * 65 + srow] = pa[pl];
                Bs[pl * 260 + sku * 65 + srow] = pb[pl];
            }
        }
        __syncthreads();
#pragma unroll
        for (int ti = 0; ti < 2; ti++) {
            s16x8 aa[3];
#pragma unroll
            for (int pl = 0; pl < 3; pl++)
                aa[pl] = As[pl * 260 + l4 * 65 + wty * 32 + ti * 16 + l15];   // + wave row offset
#pragma unroll
            for (int tj = 0; tj < 2; tj++) {
                s16x8 bb[3];
#pragma unroll
                for (int pl = 0; pl < 3; pl++)
                    bb[pl] = Bs[pl * 260 + l4 * 65 + wtx * 32 + tj * 16 + l15];   // + wave col offset
                acc[ti][tj] = __builtin_amdgcn_mfma_f32_16x16x32_bf16(aa[0], bb[0], acc[ti][tj], 0, 0, 0);
                acc[ti][tj] = __builtin_amdgcn_mfma_f32_16x16x32_bf16(aa[0], bb[1], acc[ti][tj], 0, 0, 0);
                acc[ti][tj] = __builtin_amdgcn_mfma_f32_16x16x32_bf16(aa[1], bb[0], acc[ti][tj], 0, 0, 0);
                acc[ti][tj] = __builtin_amdgcn_mfma_f32_16x16x32_bf16(aa[0], bb[2], acc[ti][tj], 0, 0, 0);
                acc[ti][tj] = __builtin_amdgcn_mfma_f32_16x16x32_bf16(aa[2], bb[0], acc[ti][tj], 0, 0, 0);
                acc[ti][tj] = __builtin_amdgcn_mfma_f32_16x16x32_bf16(aa[1], bb[1], acc[ti][tj], 0, 0, 0);
            }
        }
    }
#pragma unroll
    for (int ti = 0; ti < 2; ti++)
#pragma unroll
        for (int tj = 0; tj < 2; tj++) {
            int ccol = c0 + wtx * 32 + tj * 16 + l15;
            float bv = bin[g * CD + ccol];
#pragma unroll
            for (int r = 0; r < 4; r++) {
                int trow = t0 + wty * 32 + ti * 16 + l4 * 4 + r;
                hbuf[(size_t)trow * CD + ccol] = acc[ti][tj][r] + bv;
            }
        }
}

// ---------------- K3: fused ResidualVQ (verbatim r19) ----------------
#define STE1F(rv, cv) { float tt_ = __fsub_rn((cv), (rv)); float qq_ = __fadd_rn((rv), tt_); \
                        float rr_ = __fsub_rn((rv), qq_); lacc += (double)rr_ * rr_; (rv) = rr_; }

__global__ __launch_bounds__(256, 2) void k_rvq(const float* __restrict__ cb,
                                                float* __restrict__ ws,
                                                float* __restrict__ out,
                                                const short* __restrict__ cbt) {
    __shared__ s16x8 CbV[2][2048];
    __shared__ float cnS[KCODES];
    __shared__ double lredD[4];

    const int g  = blockIdx.y;
    const int t0 = blockIdx.x * TM;
    const int tid = threadIdx.x;
    const int lane = tid & 63, l15 = lane & 15, l4 = lane >> 4;
    const int wv = tid >> 6;
    const size_t gT = (size_t)g * T;
    const float* cng = ws + WS_CNORM + (size_t)g * Q * KCODES;
    float* hbuf = ws + WS_H;
    float* rbuf = ws + WS_RES;
    double* lpD = (double*)(ws + WS_LPARTD);

    int coff[8];
#pragma unroll
    for (int k = 0; k < 8; k++)
        coff[k] = ((wv * 8 + k) * 64 + lane) * 8;

    s16x8 fh[2][8], fl[2][8];
#pragma unroll
    for (int s = 0; s < 2; s++) {
        const float* hrow = hbuf + (gT + t0 + wv * 32 + s * 16 + l15) * CD + l4 * 8;
#pragma unroll
        for (int dc = 0; dc < 8; dc++) {
            float4 u0 = *(const float4*)(hrow + dc * 32);
            float4 u1 = *(const float4*)(hrow + dc * 32 + 4);
            float v[8] = {u0.x,u0.y,u0.z,u0.w,u1.x,u1.y,u1.z,u1.w};
            s16x8 th, tl;
#pragma unroll
            for (int e = 0; e < 8; e++) {
                unsigned short hb = f2bf(v[e]);
                th[e] = (short)hb;
                tl[e] = (short)f2bf(v[e] - bf2f(hb));
            }
            fh[s][dc] = th; fl[s][dc] = tl;
        }
    }

    for (int q = 0; q < Q; q++) {
        const float* cnq = cng + (size_t)q * KCODES;
        const double* cn64q = (const double*)(ws + WS_CN64) + ((size_t)g * Q + q) * KCODES;
        const float* cqb = cb + ((size_t)g * Q + q) * KCODES * CD;
        const short* cbtq = cbt + (size_t)(g * Q + q) * 524288;
        const float* rsrc = (q == 0) ? hbuf : rbuf;

#pragma unroll
        for (int i = 0; i < 4; i++) cnS[i * 256 + tid] = cnq[i * 256 + tid];

#pragma unroll
        for (int k = 0; k < 8; k++)
            gl_lds16(cbtq + coff[k], &CbV[0][(wv * 8 + k) * 64]);
        __syncthreads();

        float tv1[2] = {3.4e38f, 3.4e38f}, tv2[2] = {3.4e38f, 3.4e38f}, tv3[2] = {3.4e38f, 3.4e38f};
        int   tix[2] = {0x7fffffff, 0x7fffffff}, tix2[2] = {0x7fffffff, 0x7fffffff};
        f32x4 acc[2][2];
#pragma unroll
        for (int s = 0; s < 2; s++)
#pragma unroll
            for (int t = 0; t < 2; t++) acc[s][t] = (f32x4){0.f, 0.f, 0.f, 0.f};

        for (int cc = 0; cc < 32; cc++) {
            __builtin_amdgcn_s_barrier();
            if (cc + 1 < 32) {
                const int add = (cc + 1) * 16384;
#pragma unroll
                for (int k = 0; k < 8; k++)
                    gl_lds16(cbtq + add + coff[k], &CbV[(cc + 1) & 1][(wv * 8 + k) * 64]);
                asm volatile("s_waitcnt vmcnt(8)" ::: "memory");
            } else {
                asm volatile("s_waitcnt vmcnt(0)" ::: "memory");
            }
            __builtin_amdgcn_s_barrier();
            __builtin_amdgcn_sched_barrier(0);

            const int buf = cc & 1;
#pragma unroll
            for (int dc = 0; dc < 8; dc++) {
#pragma unroll
                for (int t = 0; t < 2; t++) {
                    int idx = dc * 128 + l4 * 32 + t * 16 + l15;
                    s16x8 ch = CbV[buf][idx];
                    s16x8 cl2 = CbV[buf][1024 + idx];
#pragma unroll
                    for (int s = 0; s < 2; s++) {
                        acc[s][t] = __builtin_amdgcn_mfma_f32_16x16x32_bf16(ch, fh[s][dc], acc[s][t], 0, 0, 0);
                        acc[s][t] = __builtin_amdgcn_mfma_f32_16x16x32_bf16(ch, fl[s][dc], acc[s][t], 0, 0, 0);
                        acc[s][t] = __builtin_amdgcn_mfma_f32_16x16x32_bf16(cl2, fh[s][dc], acc[s][t], 0, 0, 0);
                    }
                }
            }
#pragma unroll
            for (int s = 0; s < 2; s++)
#pragma unroll
                for (int t = 0; t < 2; t++)
#pragma unroll
                    for (int r = 0; r < 4; r++) {
                        int c = cc * 32 + t * 16 + l4 * 4 + r;
                        float vv = fmaf(-2.f, acc[s][t][r], cnS[c]);
                        if (vv < tv1[s])      { tv3[s] = tv2[s]; tv2[s] = tv1[s]; tix2[s] = tix[s]; tv1[s] = vv; tix[s] = c; }
                        else if (vv < tv2[s]) { tv3[s] = tv2[s]; tv2[s] = vv; tix2[s] = c; }
                        else if (vv < tv3[s]) { tv3[s] = vv; }
                    }
#pragma unroll
            for (int s = 0; s < 2; s++)
#pragma unroll
                for (int t = 0; t < 2; t++) acc[s][t] = (f32x4){0.f, 0.f, 0.f, 0.f};
        }

#pragma unroll
        for (int s = 0; s < 2; s++) {
#pragma unroll
            for (int m = 16; m < 64; m <<= 1) {
                float b1 = __shfl_xor(tv1[s], m, 64);
                int   bi1 = __shfl_xor(tix[s], m, 64);
                float b2 = __shfl_xor(tv2[s], m, 64);
                int   bi2 = __shfl_xor(tix2[s], m, 64);
                float b3 = __shfl_xor(tv3[s], m, 64);
                float n1, n2, n3; int ni1, ni2;
                bool bf = (b1 < tv1[s]) || (b1 == tv1[s] && bi1 < tix[s]);
                if (bf) {
                    n1 = b1; ni1 = bi1;
                    bool af = (tv1[s] < b2) || (tv1[s] == b2 && tix[s] < bi2);
                    if (af) { n2 = tv1[s]; ni2 = tix[s]; n3 = fminf(tv2[s], b2); }
                    else    { n2 = b2;     ni2 = bi2;    n3 = fminf(tv1[s], b3); }
                } else {
                    n1 = tv1[s]; ni1 = tix[s];
                    bool bs = (b1 < tv2[s]) || (b1 == tv2[s] && bi1 < tix2[s]);
                    if (bs) { n2 = b1;     ni2 = bi1;     n3 = fminf(tv2[s], b2); }
                    else    { n2 = tv2[s]; ni2 = tix2[s]; n3 = fminf(b1, tv3[s]); }
                }
                tv1[s] = n1; tix[s] = ni1; tv2[s] = n2; tix2[s] = ni2; tv3[s] = n3;
            }
        }

        int besti[2];
        bool need_full[2];
#pragma unroll 1
        for (int s = 0; s < 2; s++) {
            besti[s] = tix[s];
            need_full[s] = false;
            bool flag = (tv2[s] - tv1[s] < EPS_REFINE);
            if (!__any(flag)) continue;
            const float* rrow = rsrc + (gT + t0 + wv * 32 + s * 16 + l15) * CD + l4 * 8;
            const float* c1r = cqb + (size_t)tix[s]  * CD + l4 * 8;
            const float* c2r = cqb + (size_t)tix2[s] * CD + l4 * 8;
            double d1 = 0.0, d2 = 0.0;
#pragma unroll
            for (int dc = 0; dc < 8; dc++) {
                float4 r0 = *(const float4*)(rrow + dc * 32);
                float4 r1 = *(const float4*)(rrow + dc * 32 + 4);
                float4 p0 = *(const float4*)(c1r + dc * 32);
                float4 p1 = *(const float4*)(c1r + dc * 32 + 4);
                float4 q0 = *(const float4*)(c2r + dc * 32);
                float4 q1 = *(const float4*)(c2r + dc * 32 + 4);
                d1 = fma((double)r0.x,(double)p0.x,d1); d1 = fma((double)r0.y,(double)p0.y,d1);
                d1 = fma((double)r0.z,(double)p0.z,d1); d1 = fma((double)r0.w,(double)p0.w,d1);
                d1 = fma((double)r1.x,(double)p1.x,d1); d1 = fma((double)r1.y,(double)p1.y,d1);
                d1 = fma((double)r1.z,(double)p1.z,d1); d1 = fma((double)r1.w,(double)p1.w,d1);
                d2 = fma((double)r0.x,(double)q0.x,d2); d2 = fma((double)r0.y,(double)q0.y,d2);
                d2 = fma((double)r0.z,(double)q0.z,d2); d2 = fma((double)r0.w,(double)q0.w,d2);
                d2 = fma((double)r1.x,(double)q1.x,d2); d2 = fma((double)r1.y,(double)q1.y,d2);
                d2 = fma((double)r1.z,(double)q1.z,d2); d2 = fma((double)r1.w,(double)q1.w,d2);
            }
#pragma unroll
            for (int m = 16; m < 64; m <<= 1) {
                d1 += __shfl_xor(d1, m, 64);
                d2 += __shfl_xor(d2, m, 64);
            }
            double s1 = fma(-2.0, d1, cn64q[tix[s]]);
            double s2 = fma(-2.0, d2, cn64q[tix2[s]]);
            bool c2wins = (s2 < s1) || (s2 == s1 && tix2[s] < tix[s]);
            double swin = c2wins ? s2 : s1;
            int    iwin = c2wins ? tix2[s] : tix[s];
            if (flag) besti[s] = iwin;
            need_full[s] = flag && !(swin < (double)tv3[s] - ERRB);
        }

#pragma unroll 1
        for (int s = 0; s < 2; s++) {
            unsigned long long flg = __ballot(need_full[s]) & 0xFFFFull;
            while (flg) {
                int l = __builtin_ctzll(flg); flg &= flg - 1;
                const float4* rf4 = (const float4*)(rsrc + (gT + t0 + wv * 32 + s * 16 + l) * CD);
                double bv = 1e300; int bi = 0x7fffffff;
                for (int c = lane; c < KCODES; c += 64) {
                    const float4* cp4 = (const float4*)(cqb + (size_t)c * CD);
                    double a0=0, a1=0, a2=0, a3=0;
#pragma unroll 4
                    for (int e = 0; e < 64; e++) {
                        float4 cv = cp4[e], rv = rf4[e];
                        a0 = fma((double)rv.x,(double)cv.x,a0); a1 = fma((double)rv.y,(double)cv.y,a1);
                        a2 = fma((double)rv.z,(double)cv.z,a2); a3 = fma((double)rv.w,(double)cv.w,a3);
                    }
                    double dd = fma(-2.0, (a0+a1)+(a2+a3), cn64q[c]);
                    if (dd < bv) { bv = dd; bi = c; }
                }
#pragma unroll
                for (int m = 1; m < 64; m <<= 1) {
                    double ov = __shfl_xor(bv, m, 64);
                    int    oi = __shfl_xor(bi, m, 64);
                    if (ov < bv || (ov == bv && oi < bi)) { bv = ov; bi = oi; }
                }
                if (l15 == l) besti[s] = bi;
            }
        }

        if (lane < 16) {
#pragma unroll
            for (int s = 0; s < 2; s++)
                out[OUT_IDX + (gT + t0 + wv * 32 + s * 16 + lane) * Q + q] = (float)besti[s];
        }

        double lacc = 0.0;
#pragma unroll
        for (int s = 0; s < 2; s++) {
            size_t off = (gT + t0 + wv * 32 + s * 16 + l15) * CD + l4 * 8;
            const float* rp = rsrc + off;
            const float* crow = cqb + (size_t)besti[s] * CD + l4 * 8;
            float* wp = rbuf + off;
#pragma unroll
            for (int dc = 0; dc < 8; dc++) {
                float4 r0 = *(const float4*)(rp + dc * 32);
                float4 r1 = *(const float4*)(rp + dc * 32 + 4);
                float4 c0 = *(const float4*)(crow + dc * 32);
                float4 c1 = *(const float4*)(crow + dc * 32 + 4);
                STE1F(r0.x, c0.x); STE1F(r0.y, c0.y); STE1F(r0.z, c0.z); STE1F(r0.w, c0.w);
                STE1F(r1.x, c1.x); STE1F(r1.y, c1.y); STE1F(r1.z, c1.z); STE1F(r1.w, c1.w);
                *(float4*)(wp + dc * 32)     = r0;
                *(float4*)(wp + dc * 32 + 4) = r1;
                float v[8] = {r0.x,r0.y,r0.z,r0.w,r1.x,r1.y,r1.z,r1.w};
                s16x8 th, tl;
#pragma unroll
                for (int e = 0; e < 8; e++) {
                    unsigned short hb = f2bf(v[e]);
                    th[e] = (short)hb;
                    tl[e] = (short)f2bf(v[e] - bf2f(hb));
                }
                fh[s][dc] = th; fl[s][dc] = tl;
            }
        }

#pragma unroll
        for (int m = 1; m < 64; m <<= 1) lacc += __shfl_xor(lacc, m, 64);
        __syncthreads();
        if (lane == 0) lredD[wv] = lacc;
        __syncthreads();
        if (tid == 0)
            lpD[((size_t)g * Q + q) * 256 + blockIdx.x] =
                ((lredD[0] + lredD[1]) + (lredD[2] + lredD[3]));
        __syncthreads();
    }
}

// ---------------- K4: out = (h - res) @ Wout_g^T + bout (3-product MFMA) ----------------
__global__ __launch_bounds__(256) void k_proj_out(const float* __restrict__ ws,
                                                  const float* __restrict__ Wout,
                                                  const float* __restrict__ bout,
                                                  float* __restrict__ out) {
    __shared__ s16x8 As[520];    // 2 planes * 4 ku * 65
    __shared__ s16x8 Bs[520];
    const int g  = blockIdx.z;
    const int t0 = blockIdx.x * 64;
    const int d0 = blockIdx.y * 64;
    const int tid = threadIdx.x;
    const int lane = tid & 63, l15 = lane & 15, l4 = lane >> 4;
    const int wv = tid >> 6, wty = wv >> 1, wtx = wv & 1;
    const int srow = tid >> 2, sku = tid & 3;
    const float* Ah = ws + WS_H + (size_t)g * T * CD;
    const float* Ar = ws + WS_RES + (size_t)g * T * CD;
    const float* Bg = Wout + (size_t)g * DG * CD;

    f32x4 acc[2][2];
#pragma unroll
    for (int i = 0; i < 2; i++)
#pragma unroll
        for (int j = 0; j < 2; j++) acc[i][j] = (f32x4){0.f,0.f,0.f,0.f};

    for (int k0 = 0; k0 < CD; k0 += 32) {
        size_t ao = (size_t)(t0 + srow) * CD + k0 + sku * 8;
        const float* bp = Bg + (size_t)(d0 + srow) * CD + k0 + sku * 8;
        float4 h0 = *(const float4*)(Ah + ao), h1 = *(const float4*)(Ah + ao + 4);
        float4 r0 = *(const float4*)(Ar + ao), r1 = *(const float4*)(Ar + ao + 4);
        float4 b0 = *(const float4*)bp, b1 = *(const float4*)(bp + 4);
        __syncthreads();
        {
            float va[8] = {h0.x-r0.x, h0.y-r0.y, h0.z-r0.z, h0.w-r0.w,
                           h1.x-r1.x, h1.y-r1.y, h1.z-r1.z, h1.w-r1.w};
            float vb[8] = {b0.x,b0.y,b0.z,b0.w,b1.x,b1.y,b1.z,b1.w};
            s16x8 pa[2], pb[2];
#pragma unroll
            for (int e = 0; e < 8; e++) {
                float v = va[e];
                unsigned short q1 = f2bf(v);
                pa[0][e] = (short)q1; pa[1][e] = (short)f2bf(v - bf2f(q1));
                v = vb[e];
                q1 = f2bf(v);
                pb[0][e] = (short)q1; pb[1][e] = (short)f2bf(v - bf2f(q1));
            }
#pragma unroll
            for (int pl = 0; pl < 2; pl++) {
                As[pl * 260 + sku * 65 + srow] = pa[pl];
                Bs[pl * 260 + sku * 65 + srow] = pb[pl];
            }
        }
        __syncthreads();
#pragma unroll
        for (int ti = 0; ti < 2; ti++) {
            s16x8 a0f = As[l4 * 65 + wty * 32 + ti * 16 + l15];          // + wave row offset
            s16x8 a1f = As[260 + l4 * 65 + wty * 32 + ti * 16 + l15];
#pragma unroll
            for (int tj = 0; tj < 2; tj++) {
                s16x8 b0f = Bs[l4 * 65 + wtx * 32 + tj * 16 + l15];      // + wave col offset
                s16x8 b1f = Bs[260 + l4 * 65 + wtx * 32 + tj * 16 + l15];
                acc[ti][tj] = __builtin_amdgcn_mfma_f32_16x16x32_bf16(a0f, b0f, acc[ti][tj], 0, 0, 0);
                acc[ti][tj] = __builtin_amdgcn_mfma_f32_16x16x32_bf16(a0f, b1f, acc[ti][tj], 0, 0, 0);
                acc[ti][tj] = __builtin_amdgcn_mfma_f32_16x16x32_bf16(a1f, b0f, acc[ti][tj], 0, 0, 0);
            }
        }
    }
#pragma unroll
    for (int ti = 0; ti < 2; ti++)
#pragma unroll
        for (int tj = 0; tj < 2; tj++) {
            int dcol = d0 + wtx * 32 + tj * 16 + l15;
            float bv = bout[g * DG + dcol];
#pragma unroll
            for (int r = 0; r < 4; r++) {
                int trow = t0 + wty * 32 + ti * 16 + l4 * 4 + r;
                out[(size_t)trow * DIMV + (size_t)g * DG + dcol] = acc[ti][tj][r] + bv;
            }
        }
}

// ---------------- K5: deterministic loss reduction (f64 -> f32) ----------------
__global__ void k_loss(const float* __restrict__ ws, float* __restrict__ out) {
    int gq = blockIdx.x;
    const double* lpD = (const double*)(ws + WS_LPARTD);
    double v = lpD[(size_t)gq * 256 + threadIdx.x];
#pragma unroll
    for (int m = 1; m < 64; m <<= 1) v += __shfl_xor(v, m, 64);
    __shared__ double red[4];
    if ((threadIdx.x & 63) == 0) red[threadIdx.x >> 6] = v;
    __syncthreads();
    if (threadIdx.x == 0)
        out[OUT_LOSS + gq] =
            (float)(((red[0] + red[1]) + (red[2] + red[3])) * (1.0 / 8388608.0));
}

extern "C" void kernel_launch(void* const* d_in, const int* in_sizes, int n_in,
                              void* d_out, int out_size, void* d_ws, size_t ws_size,
                              hipStream_t stream) {
    const float* x    = (const float*)d_in[0];
    const float* Win  = (const float*)d_in[1];
    const float* bin  = (const float*)d_in[2];
    const float* Wout = (const float*)d_in[3];
    const float* bout = (const float*)d_in[4];
    const float* cb   = (const float*)d_in[5];
    float* out = (float*)d_out;
    float* ws  = (float*)d_ws;

    // Pre-transposed bf16 hi/lo codebook in the not-yet-written quantized
    // region of d_out: 8.4M shorts = 4.2M f32-equiv << 41.9M f32 region.
    short* cbt = (short*)d_out;

    hipLaunchKernelGGL(k_norms,    dim3(64),          dim3(256), 0, stream, cb, ws);
    hipLaunchKernelGGL(k_split,    dim3(2048),        dim3(256), 0, stream, cb, cbt);
    hipLaunchKernelGGL(k_proj_in,  dim3(T/64, 4, G),  dim3(256), 0, stream, x, Win, bin, ws);
    hipLaunchKernelGGL(k_rvq,      dim3(T/TM, G),     dim3(256), 0, stream, cb, ws, out, cbt);
    hipLaunchKernelGGL(k_proj_out, dim3(T/64, 10, G), dim3(256), 0, stream, ws, Wout, bout, out);
    hipLaunchKernelGGL(k_loss,     dim3(16),          dim3(256), 0, stream, ws, out);
}